// Round 5
// baseline (271.743 us; speedup 1.0000x reference)
//
#include <hip/hip_runtime.h>
#include <stdint.h>

// WebAttention fused block for MI355X (gfx950).
// R5: attention as a uniform work-queue: every wave = one (head, q-tile, 8-key-block
//     chunk), 9216 waves of <=8 iters each (no ragged tail). bf16 partials + online
//     merge in attn_combine. GEMM/preps unchanged from R4.

typedef unsigned short u16;
typedef unsigned short u16x4 __attribute__((ext_vector_type(4)));
typedef unsigned short u16x8 __attribute__((ext_vector_type(8)));
typedef __bf16 bf16x8 __attribute__((ext_vector_type(8)));
typedef float f32x4 __attribute__((ext_vector_type(4)));
typedef float f32x16 __attribute__((ext_vector_type(16)));

#define SLEN 2048
#define HIDDEN 2048
#define QKVN 3072   // 2048 Q + 512 K + 512 V
// Q pre-scale: 1/sqrt(64) * log2(e)  -> scores land in exp2 domain
#define QSCALE 0.18033688011112042f
#define NSLOT_A 5120   // partial slots in region A (20 MB), rest in region B

__device__ __forceinline__ u16 f2bf(float x) {  // RNE, matches numpy/JAX
  uint32_t u = __float_as_uint(x);
  return (u16)((u + 0x7FFFu + ((u >> 16) & 1u)) >> 16);
}

__device__ __forceinline__ uint32_t cvtpk_bf16(float lo, float hi) {
  uint32_t r;
  asm("v_cvt_pk_bf16_f32 %0, %1, %2" : "=v"(r) : "v"(lo), "v"(hi));
  return r;
}

__device__ __forceinline__ void gload_lds16(const void* g, void* l) {
  __builtin_amdgcn_global_load_lds(
      (const __attribute__((address_space(1))) void*)g,
      (__attribute__((address_space(3))) void*)l, 16, 0, 0);
}

// ---------------- prep kernels ----------------

__global__ __launch_bounds__(256) void cvt_f32_bf16(const float* __restrict__ in,
                                                    u16* __restrict__ out) {
  int idx = (blockIdx.x * 256 + threadIdx.x) * 4;
  float4 v = *(const float4*)(in + idx);
  u16x4 o;
  o[0] = f2bf(v.x); o[1] = f2bf(v.y); o[2] = f2bf(v.z); o[3] = f2bf(v.w);
  *(u16x4*)(out + idx) = o;
}

// in: f32 [K][ldin] row-major; out: bf16 [N][ldout] = transpose. grid (K/32, N/32).
__global__ __launch_bounds__(256) void transpose_w(const float* __restrict__ in, int ldin,
                                                   u16* __restrict__ out, int ldout) {
  __shared__ float tile[32][33];
  int k0 = blockIdx.x * 32, n0 = blockIdx.y * 32;
  int x = threadIdx.x & 31, y = threadIdx.x >> 5;  // y in 0..7
#pragma unroll
  for (int i = 0; i < 32; i += 8)
    tile[y + i][x] = in[(size_t)(k0 + y + i) * ldin + n0 + x];
  __syncthreads();
#pragma unroll
  for (int i = 0; i < 32; i += 8)
    out[(size_t)(n0 + y + i) * ldout + k0 + x] = f2bf(tile[x][y + i]);
}

// web mask [S][S] f32 (0 / -1e9) -> bitmask [S][64] u32 (bit=1 -> keep)
__global__ __launch_bounds__(256) void pack_mask(const float* __restrict__ m,
                                                 uint32_t* __restrict__ bits) {
  int w = blockIdx.x * 256 + threadIdx.x;  // 2048*64 words
  const float* p = m + (size_t)w * 32;
  uint32_t b = 0;
#pragma unroll
  for (int j = 0; j < 32; ++j) b |= (p[j] > -0.5f ? 1u : 0u) << j;
  bits[w] = b;
}

// ---------------- TN GEMM: C[M][N] = A[M][K] * B[N][K]^T (bf16 in, fp32 out) --------
// 64x128 tile, BK=64, 4 waves (2x2), 32x64 per wave, fragment-ordered LDS.
__global__ __launch_bounds__(256) void gemm_tn(const u16* __restrict__ A,
                                               const u16* __restrict__ B,
                                               float* __restrict__ C,
                                               int M, int N, int K) {
  __shared__ u16 As[64 * 64];    // 8 KB
  __shared__ u16 Bs[128 * 64];   // 16 KB
  const int tid = threadIdx.x;
  const int w = tid >> 6, l = tid & 63;
  const int bm = blockIdx.x, bn = blockIdx.y;
  const int wr = w >> 1, wc = w & 1;

  f32x4 acc[2][4] = {};

  int rowA[2], colA[2], ldsA[2];
#pragma unroll
  for (int g = 0; g < 2; ++g) {
    int c = g * 256 + w * 64 + l;
    rowA[g] = ((c >> 7) << 4) + (c & 15);
    colA[g] = ((c >> 4) & 7) * 8;
    ldsA[g] = (g * 256 + w * 64) * 8;
  }
  int rowB[4], colB[4], ldsB[4];
#pragma unroll
  for (int g = 0; g < 4; ++g) {
    int c = g * 256 + w * 64 + l;
    rowB[g] = ((c >> 7) << 4) + (c & 15);
    colB[g] = ((c >> 4) & 7) * 8;
    ldsB[g] = (g * 256 + w * 64) * 8;
  }
  const u16* Arow = A + (size_t)(bm * 64) * K;
  const u16* Brow = B + (size_t)(bn * 128) * K;

  for (int k0 = 0; k0 < K; k0 += 64) {
    __syncthreads();
#pragma unroll
    for (int g = 0; g < 2; ++g)
      gload_lds16(Arow + (size_t)rowA[g] * K + k0 + colA[g], &As[ldsA[g]]);
#pragma unroll
    for (int g = 0; g < 4; ++g)
      gload_lds16(Brow + (size_t)rowB[g] * K + k0 + colB[g], &Bs[ldsB[g]]);
    asm volatile("s_waitcnt vmcnt(0)" ::: "memory");
    __syncthreads();
#pragma unroll
    for (int ks = 0; ks < 2; ++ks) {
      bf16x8 af[2], bfr[4];
#pragma unroll
      for (int mi = 0; mi < 2; ++mi)
        af[mi] = *(const bf16x8*)&As[(wr * 2 + mi) * 1024 + ks * 512 + l * 8];
#pragma unroll
      for (int ni = 0; ni < 4; ++ni)
        bfr[ni] = *(const bf16x8*)&Bs[(wc * 4 + ni) * 1024 + ks * 512 + l * 8];
#pragma unroll
      for (int mi = 0; mi < 2; ++mi)
#pragma unroll
        for (int ni = 0; ni < 4; ++ni)
          acc[mi][ni] = __builtin_amdgcn_mfma_f32_16x16x32_bf16(af[mi], bfr[ni],
                                                                acc[mi][ni], 0, 0, 0);
    }
  }
  const int cr = (l >> 4) * 4, cc = l & 15;
#pragma unroll
  for (int mi = 0; mi < 2; ++mi) {
    int row0 = bm * 64 + wr * 32 + mi * 16 + cr;
#pragma unroll
    for (int ni = 0; ni < 4; ++ni) {
      int col = bn * 128 + wc * 64 + ni * 16 + cc;
#pragma unroll
      for (int i = 0; i < 4; ++i)
        C[(size_t)(row0 + i) * N + col] = acc[mi][ni][i];
    }
  }
}

// ---------------- RoPE + RMSNorm epilogue ----------------
__global__ __launch_bounds__(256) void rope_rms(const float* __restrict__ qkv,
                                                const float* __restrict__ qw,
                                                const float* __restrict__ kw,
                                                u16* __restrict__ Qo,
                                                u16* __restrict__ Ko) {
  int s = blockIdx.x * 4 + (threadIdx.x >> 6);
  int hh = blockIdx.y;
  int d = threadIdx.x & 63;
  bool isq = hh < 32;
  int col = isq ? hh * 64 + d : 2048 + (hh - 32) * 64 + d;
  float x = qkv[(size_t)s * QKVN + col];
  int i = d & 31;
  float inv_freq = exp2f(-(float)i * (13.287712379549449f / 32.0f));
  float ang = (float)s * inv_freq;
  float sn, cs;
  __sincosf(ang, &sn, &cs);
  float partner = __shfl_xor(x, 32, 64);
  float y = (d < 32) ? (x * cs - partner * sn) : (x * cs + partner * sn);
  float ss = y * y;
#pragma unroll
  for (int off = 32; off; off >>= 1) ss += __shfl_xor(ss, off, 64);
  float r = rsqrtf(ss * (1.0f / 64.0f) + 1e-6f);
  float o = y * r * (isq ? qw[d] : kw[d]);
  if (isq) Qo[((size_t)hh * SLEN + s) * 64 + d] = f2bf(o * QSCALE);
  else     Ko[((size_t)(hh - 32) * SLEN + s) * 64 + d] = f2bf(o);
}

// V slice of QKV -> V^T bf16 [8][64][S]
__global__ __launch_bounds__(256) void v_trans(const float* __restrict__ qkv,
                                               u16* __restrict__ Vt) {
  __shared__ float tile[32][65];
  int kv = blockIdx.y;
  int s0 = blockIdx.x * 32;
  int tid = threadIdx.x;
  int d = tid & 63, r4 = tid >> 6;
#pragma unroll
  for (int i = 0; i < 32; i += 4)
    tile[i + r4][d] = qkv[(size_t)(s0 + i + r4) * QKVN + 2560 + kv * 64 + d];
  __syncthreads();
  int dr = tid >> 2, sc = (tid & 3) * 8;
  u16x8 o;
#pragma unroll
  for (int j = 0; j < 8; ++j) o[j] = f2bf(tile[sc + j][dr]);
  *(u16x8*)(Vt + ((size_t)(kv * 64 + dr)) * SLEN + s0 + sc) = o;
}

// ---------------- flash attention, uniform 8-block chunks ----------------
// grid (8, 288): block (x,y) -> 4 waves = heads 4x..4x+3, all at chunk y.
// Chunk y -> (qt, j): group g occupies y in [4g(g+1), 4(g+1)(g+2)), size 8(g+1);
// off = y - 4g(g+1); qt = 8g + (off&7); j = off>>3; keys kb in [8j, min(8j+8, qt+1)).
// Every wave runs <=8 key-block iters -> uniform work-queue, no tail.
// Partial slot = h*288 + y: bf16 [32 q][64 d] (4 KB) + (m,l) f32 per q-row.
__global__ __launch_bounds__(256) void attn_split(const u16* __restrict__ Q,
                                                  const u16* __restrict__ Kh,
                                                  const u16* __restrict__ Vt,
                                                  const uint32_t* __restrict__ mbits,
                                                  u16* __restrict__ pA,
                                                  u16* __restrict__ pB,
                                                  float2* __restrict__ ml) {
  const int w = threadIdx.x >> 6, l = threadIdx.x & 63;
  const int h = blockIdx.x * 4 + w;
  const int y = blockIdx.y;
  int g = (int)((sqrtf((float)y + 1.0f) - 1.0f) * 0.5f);
  while (4 * (g + 1) * (g + 2) <= y) ++g;   // fixup (float-safe)
  while (4 * g * (g + 1) > y) --g;
  const int off = y - 4 * g * (g + 1);
  const int qt = 8 * g + (off & 7);
  const int j = off >> 3;
  const int kb0 = 8 * j;
  const int kbe = min(8 * j + 8, qt + 1);   // non-empty: 8j <= qt always

  const int q0 = qt * 32;
  const int hkv = h >> 2;
  const bool web = (h >= 16);
  const int l31 = l & 31, hi = l >> 5;
  const int qrel = l31 - 4 * hi;  // diag-block causal: keep iff ki <= qrel

  // Q B-frags (col=lane&31=q, k=hi*8+jj), D=64 -> 4 frags
  const u16* Qp = Q + ((size_t)h * SLEN + q0 + l31) * 64 + hi * 8;
  bf16x8 qf0 = *(const bf16x8*)(Qp);
  bf16x8 qf1 = *(const bf16x8*)(Qp + 16);
  bf16x8 qf2 = *(const bf16x8*)(Qp + 32);
  bf16x8 qf3 = *(const bf16x8*)(Qp + 48);

  const u16* Kp = Kh + ((size_t)hkv * SLEN + l31) * 64 + hi * 8;
  const u16* Vp = Vt + ((size_t)hkv * 64 + l31) * SLEN + hi * 8;
  const uint32_t* mrow = mbits + (size_t)(q0 + l31) * 64;

  f32x16 acc0 = {}, acc1 = {};   // O^T[d][q]
  float m = -1e30f, ll = 0.f;

  // prefetch first K block + mask word
  const u16* kp = Kp + (size_t)kb0 * 64 * 32;
  bf16x8 kc0 = *(const bf16x8*)(kp);
  bf16x8 kc1 = *(const bf16x8*)(kp + 16);
  bf16x8 kc2 = *(const bf16x8*)(kp + 32);
  bf16x8 kc3 = *(const bf16x8*)(kp + 48);
  uint32_t wcur = web ? mrow[kb0] : 0u;

  for (int kb = kb0; kb < kbe; ++kb) {
    const int k0 = kb * 32;
    // V loads for this block issued early (consumed after softmax)
    const u16* vp = Vp + k0;
    bf16x8 vf00 = *(const bf16x8*)(vp);
    bf16x8 vf01 = *(const bf16x8*)(vp + 16);
    bf16x8 vf10 = *(const bf16x8*)(vp + 32 * SLEN);
    bf16x8 vf11 = *(const bf16x8*)(vp + 32 * SLEN + 16);
    // prefetch next K block + mask word
    bf16x8 kn0, kn1, kn2, kn3;
    uint32_t wnext = 0u;
    if (kb + 1 < kbe) {
      const u16* knp = Kp + (size_t)(kb + 1) * 64 * 32;
      kn0 = *(const bf16x8*)(knp);
      kn1 = *(const bf16x8*)(knp + 16);
      kn2 = *(const bf16x8*)(knp + 32);
      kn3 = *(const bf16x8*)(knp + 48);
      if (web) wnext = mrow[kb + 1];
    }
    // ---- S^T = K * Q ----
    f32x16 s = {};
    s = __builtin_amdgcn_mfma_f32_32x32x16_bf16(kc0, qf0, s, 0, 0, 0);
    s = __builtin_amdgcn_mfma_f32_32x32x16_bf16(kc1, qf1, s, 0, 0, 0);
    s = __builtin_amdgcn_mfma_f32_32x32x16_bf16(kc2, qf2, s, 0, 0, 0);
    s = __builtin_amdgcn_mfma_f32_32x32x16_bf16(kc3, qf3, s, 0, 0, 0);
    // ---- mask (exp2 domain; masked -> -1e9) ----
    if (web) {
      uint32_t word = wcur >> (hi * 4);
      if (kb == qt) {
#pragma unroll
        for (int r = 0; r < 16; ++r) {
          const int ki = (r & 3) + 8 * (r >> 2);
          bool keep = ((word >> ki) & 1u) && (ki <= qrel);
          s[r] = keep ? s[r] : -1e9f;
        }
      } else {
#pragma unroll
        for (int r = 0; r < 16; ++r) {
          const int ki = (r & 3) + 8 * (r >> 2);
          s[r] = ((word >> ki) & 1u) ? s[r] : -1e9f;
        }
      }
    } else if (kb == qt) {
#pragma unroll
      for (int r = 0; r < 16; ++r) {
        const int ki = (r & 3) + 8 * (r >> 2);
        s[r] = (ki <= qrel) ? s[r] : -1e9f;
      }
    }
    // ---- online softmax (lane-local row) ----
    float pm = s[0];
#pragma unroll
    for (int r = 1; r < 16; ++r) pm = fmaxf(pm, s[r]);
    pm = fmaxf(pm, __shfl_xor(pm, 32));
    if (__any(pm > m + 8.0f)) {           // defer-max, log2 units
      float nm = fmaxf(m, pm);
      float al = exp2f(m - nm);
#pragma unroll
      for (int r = 0; r < 16; ++r) { acc0[r] *= al; acc1[r] *= al; }
      ll *= al;
      m = nm;
    }
    f32x16 p;
#pragma unroll
    for (int r = 0; r < 16; ++r) p[r] = exp2f(s[r] - m);
    float rs = 0.f;
#pragma unroll
    for (int r = 0; r < 16; ++r) rs += p[r];
    rs += __shfl_xor(rs, 32);
    ll += rs;
    // ---- P^T -> bf16 B-frags: cvt_pk + xor-32 redistribute ----
    uint32_t a0 = cvtpk_bf16(p[0], p[1]),   b0 = cvtpk_bf16(p[2], p[3]);
    uint32_t c0 = cvtpk_bf16(p[4], p[5]),   d0 = cvtpk_bf16(p[6], p[7]);
    uint32_t a1 = cvtpk_bf16(p[8], p[9]),   b1 = cvtpk_bf16(p[10], p[11]);
    uint32_t c1 = cvtpk_bf16(p[12], p[13]), d1 = cvtpk_bf16(p[14], p[15]);
    uint32_t ax0 = __shfl_xor(a0, 32), bx0 = __shfl_xor(b0, 32);
    uint32_t cx0 = __shfl_xor(c0, 32), dx0 = __shfl_xor(d0, 32);
    uint32_t ax1 = __shfl_xor(a1, 32), bx1 = __shfl_xor(b1, 32);
    uint32_t cx1 = __shfl_xor(c1, 32), dx1 = __shfl_xor(d1, 32);
    union { uint32_t w[4]; bf16x8 v; } pf0u, pf1u;
    pf0u.w[0] = hi ? cx0 : a0;  pf0u.w[1] = hi ? dx0 : b0;
    pf0u.w[2] = hi ? c0 : ax0;  pf0u.w[3] = hi ? d0 : bx0;
    pf1u.w[0] = hi ? cx1 : a1;  pf1u.w[1] = hi ? dx1 : b1;
    pf1u.w[2] = hi ? c1 : ax1;  pf1u.w[3] = hi ? d1 : bx1;
    // ---- O^T += V^T * P^T ----
    acc0 = __builtin_amdgcn_mfma_f32_32x32x16_bf16(vf00, pf0u.v, acc0, 0, 0, 0);
    acc0 = __builtin_amdgcn_mfma_f32_32x32x16_bf16(vf01, pf1u.v, acc0, 0, 0, 0);
    acc1 = __builtin_amdgcn_mfma_f32_32x32x16_bf16(vf10, pf0u.v, acc1, 0, 0, 0);
    acc1 = __builtin_amdgcn_mfma_f32_32x32x16_bf16(vf11, pf1u.v, acc1, 0, 0, 0);
    // rotate prefetch
    kc0 = kn0; kc1 = kn1; kc2 = kn2; kc3 = kn3; wcur = wnext;
  }
  // ---- store bf16 partial [32 q][64 d] + (m,l) ----
  const int slot = h * 288 + y;
  u16* prow = (slot < NSLOT_A ? pA + (size_t)slot * 2048
                              : pB + (size_t)(slot - NSLOT_A) * 2048) + l31 * 64;
#pragma unroll
  for (int t = 0; t < 4; ++t) {
    uint2 p0, p1;
    p0.x = cvtpk_bf16(acc0[4 * t], acc0[4 * t + 1]);
    p0.y = cvtpk_bf16(acc0[4 * t + 2], acc0[4 * t + 3]);
    p1.x = cvtpk_bf16(acc1[4 * t], acc1[4 * t + 1]);
    p1.y = cvtpk_bf16(acc1[4 * t + 2], acc1[4 * t + 3]);
    *(uint2*)(prow + 8 * t + 4 * hi) = p0;        // d = 8t+4hi..+3
    *(uint2*)(prow + 32 + 8 * t + 4 * hi) = p1;   // d = 32+8t+4hi..+3
  }
  if (hi == 0) ml[(size_t)slot * 32 + l31] = make_float2(m, ll);
}

// ---------------- combine chunk partials -> Ao bf16 [S][H*D] ----------------
// grid 512 x 256thr: wave idx = h*64+qt; lane = (q=l&31, dhalf=l>>5).
// Online-softmax merge over the g+1 slots of tile qt (static-index regs only).
__global__ __launch_bounds__(256) void attn_combine(const u16* __restrict__ pA,
                                                    const u16* __restrict__ pB,
                                                    const float2* __restrict__ ml,
                                                    u16* __restrict__ Aout) {
  const int w = threadIdx.x >> 6, l = threadIdx.x & 63;
  const int idx = blockIdx.x * 4 + w;        // h*64 + qt
  const int h = idx >> 6, qt = idx & 63;
  const int l31 = l & 31, hi = l >> 5;
  const int g = qt >> 3, lt = qt & 7;
  const int sbase = h * 288 + 4 * g * (g + 1) + lt;  // + j*8

  float M = -3.0e38f, L = 0.f;
  float o[32] = {};
  for (int j = 0; j <= g; ++j) {
    const int slot = sbase + j * 8;
    float2 v = ml[(size_t)slot * 32 + l31];
    float scale_, w_;
    if (v.x > M) { scale_ = exp2f(M - v.x); w_ = 1.f; M = v.x; }
    else         { scale_ = 1.f; w_ = exp2f(v.x - M); }
    L = L * scale_ + v.y * w_;
    const u16* p = (slot < NSLOT_A ? pA + (size_t)slot * 2048
                                   : pB + (size_t)(slot - NSLOT_A) * 2048)
                   + l31 * 64 + hi * 32;
#pragma unroll
    for (int t = 0; t < 4; ++t) {
      u16x8 vv = *(const u16x8*)(p + t * 8);
#pragma unroll
      for (int e = 0; e < 8; ++e)
        o[t * 8 + e] = o[t * 8 + e] * scale_ +
                       w_ * __uint_as_float((uint32_t)vv[e] << 16);
    }
  }
  const float invL = 1.0f / L;
  u16* orow = Aout + (size_t)(qt * 32 + l31) * HIDDEN + h * 64 + hi * 32;
#pragma unroll
  for (int t = 0; t < 4; ++t) {
    uint2 pk;
    pk.x = cvtpk_bf16(o[t * 8 + 0] * invL, o[t * 8 + 1] * invL);
    pk.y = cvtpk_bf16(o[t * 8 + 2] * invL, o[t * 8 + 3] * invL);
    uint2 pk2;
    pk2.x = cvtpk_bf16(o[t * 8 + 4] * invL, o[t * 8 + 5] * invL);
    pk2.y = cvtpk_bf16(o[t * 8 + 6] * invL, o[t * 8 + 7] * invL);
    *(uint2*)(orow + t * 8) = pk;
    *(uint2*)(orow + t * 8 + 4) = pk2;
  }
}

// ---------------- launch ----------------

extern "C" void kernel_launch(void* const* d_in, const int* in_sizes, int n_in,
                              void* d_out, int out_size, void* d_ws, size_t ws_size,
                              hipStream_t stream) {
  const float* hidden  = (const float*)d_in[0];
  const float* webmask = (const float*)d_in[3];
  const float* Wq = (const float*)d_in[4];
  const float* Wk = (const float*)d_in[5];
  const float* Wv = (const float*)d_in[6];
  const float* Wo = (const float*)d_in[7];
  const float* qlnw = (const float*)d_in[8];
  const float* klnw = (const float*)d_in[9];
  float* out = (float*)d_out;

  char* ws = (char*)d_ws;
  u16*      hbf  = (u16*)(ws);                         // 8 MB  hidden bf16 (dead after QKV gemm)
  u16*      Wcat = (u16*)(ws + (8u << 20));            // 12 MB QKV weights^T (dead after QKV gemm)
  u16*      Wot  = (u16*)(ws + (20u << 20));           // 8 MB  Wo^T (live until final gemm)
  float*    qkv  = (float*)(ws + (28u << 20));         // 24 MB QKV fp32 (dead after rope/v_trans)
  u16*      Qh   = (u16*)(ws + (52u << 20));           // 8 MB  Q' (pre-scaled)
  u16*      Kh   = (u16*)(ws + (60u << 20));           // 2 MB  K'
  u16*      Vt   = (u16*)(ws + (62u << 20));           // 2 MB  V^T
  u16*      Ao   = (u16*)(ws + (64u << 20));           // 8 MB  attn out bf16
  uint32_t* mb   = (uint32_t*)(ws + (72u << 20));      // 0.5 MB web mask bits
  // chunk partials overlay dead regions:
  u16*      pA   = (u16*)(ws);                         // 20 MB: slots 0..5119 (hbf+Wcat)
  u16*      pB   = (u16*)(ws + (28u << 20));           // 16 MB: slots 5120..9215 (qkv)
  float2*   pml  = (float2*)(ws + (44u << 20));        // 2.4 MB (qkv tail)

  cvt_f32_bf16<<<4096, 256, 0, stream>>>(hidden, hbf);
  transpose_w<<<dim3(64, 64), 256, 0, stream>>>(Wq, 2048, Wcat, 2048);
  transpose_w<<<dim3(64, 16), 256, 0, stream>>>(Wk, 512, Wcat + (size_t)2048 * 2048, 2048);
  transpose_w<<<dim3(64, 16), 256, 0, stream>>>(Wv, 512, Wcat + (size_t)2560 * 2048, 2048);
  transpose_w<<<dim3(64, 64), 256, 0, stream>>>(Wo, 2048, Wot, 2048);
  pack_mask<<<512, 256, 0, stream>>>(webmask, mb);

  gemm_tn<<<dim3(32, 24), 256, 0, stream>>>(hbf, Wcat, qkv, SLEN, QKVN, HIDDEN);
  rope_rms<<<dim3(512, 40), 256, 0, stream>>>(qkv, qlnw, klnw, Qh, Kh);
  v_trans<<<dim3(64, 8), 256, 0, stream>>>(qkv, Vt);
  attn_split<<<dim3(8, 288), 256, 0, stream>>>(Qh, Kh, Vt, mb, pA, pB, pml);
  attn_combine<<<512, 256, 0, stream>>>(pA, pB, pml, Ao);
  gemm_tn<<<dim3(32, 16), 256, 0, stream>>>(Ao, Wot, out, SLEN, HIDDEN, HIDDEN);
}

// Round 8
// 257.021 us; speedup vs baseline: 1.0573x; 1.0573x over previous
//
#include <hip/hip_runtime.h>
#include <stdint.h>

// WebAttention fused block for MI355X (gfx950).
// R8: fix permlane32_swap operand order. Semantics (CDNA4):
//   v_permlane32_swap_b32 vdst, vsrc: vdst.upper <-> vsrc.lower; builtin returns
//   {vdst', vsrc'}. For P-frags: swap(lowpack, highpack) -> r[0]=w_low, r[1]=w_high
//   (matches guide T12 recipe). R7 had operands reversed -> wrong halves.

typedef unsigned short u16;
typedef unsigned short u16x4 __attribute__((ext_vector_type(4)));
typedef unsigned short u16x8 __attribute__((ext_vector_type(8)));
typedef __bf16 bf16x8 __attribute__((ext_vector_type(8)));
typedef float f32x4 __attribute__((ext_vector_type(4)));
typedef float f32x16 __attribute__((ext_vector_type(16)));

#define SLEN 2048
#define HIDDEN 2048
#define QKVN 3072   // 2048 Q + 512 K + 512 V
// Q pre-scale: 1/sqrt(64) * log2(e)  -> scores land in exp2 domain
#define QSCALE 0.18033688011112042f

__device__ __forceinline__ u16 f2bf(float x) {  // RNE, matches numpy/JAX
  uint32_t u = __float_as_uint(x);
  return (u16)((u + 0x7FFFu + ((u >> 16) & 1u)) >> 16);
}

__device__ __forceinline__ uint32_t cvtpk_bf16(float lo, float hi) {
  uint32_t r;
  asm("v_cvt_pk_bf16_f32 %0, %1, %2" : "=v"(r) : "v"(lo), "v"(hi));
  return r;
}

// Cross-half (lane ^ 32) reductions: {r[0],r[1]} = {self, partner} as a set for
// every lane regardless of swap direction -> safe for commutative ops.
__device__ __forceinline__ float xhalf_max(float x) {
  auto r = __builtin_amdgcn_permlane32_swap(__float_as_uint(x), __float_as_uint(x),
                                            false, false);
  return fmaxf(__uint_as_float(r[0]), __uint_as_float(r[1]));
}

__device__ __forceinline__ float xhalf_sum(float x) {
  auto r = __builtin_amdgcn_permlane32_swap(__float_as_uint(x), __float_as_uint(x),
                                            false, false);
  return __uint_as_float(r[0]) + __uint_as_float(r[1]);
}

__device__ __forceinline__ void gload_lds16(const void* g, void* l) {
  __builtin_amdgcn_global_load_lds(
      (const __attribute__((address_space(1))) void*)g,
      (__attribute__((address_space(3))) void*)l, 16, 0, 0);
}

// ---------------- prep kernels ----------------

__global__ __launch_bounds__(256) void cvt_f32_bf16(const float* __restrict__ in,
                                                    u16* __restrict__ out) {
  int idx = (blockIdx.x * 256 + threadIdx.x) * 4;
  float4 v = *(const float4*)(in + idx);
  u16x4 o;
  o[0] = f2bf(v.x); o[1] = f2bf(v.y); o[2] = f2bf(v.z); o[3] = f2bf(v.w);
  *(u16x4*)(out + idx) = o;
}

// in: f32 [K][ldin] row-major; out: bf16 [N][ldout] = transpose. grid (K/32, N/32).
__global__ __launch_bounds__(256) void transpose_w(const float* __restrict__ in, int ldin,
                                                   u16* __restrict__ out, int ldout) {
  __shared__ float tile[32][33];
  int k0 = blockIdx.x * 32, n0 = blockIdx.y * 32;
  int x = threadIdx.x & 31, y = threadIdx.x >> 5;  // y in 0..7
#pragma unroll
  for (int i = 0; i < 32; i += 8)
    tile[y + i][x] = in[(size_t)(k0 + y + i) * ldin + n0 + x];
  __syncthreads();
#pragma unroll
  for (int i = 0; i < 32; i += 8)
    out[(size_t)(n0 + y + i) * ldout + k0 + x] = f2bf(tile[x][y + i]);
}

// web mask [S][S] f32 (0 / -1e9) -> bitmask [S][64] u32 (bit=1 -> keep)
__global__ __launch_bounds__(256) void pack_mask(const float* __restrict__ m,
                                                 uint32_t* __restrict__ bits) {
  int w = blockIdx.x * 256 + threadIdx.x;  // 2048*64 words
  const float* p = m + (size_t)w * 32;
  uint32_t b = 0;
#pragma unroll
  for (int j = 0; j < 32; ++j) b |= (p[j] > -0.5f ? 1u : 0u) << j;
  bits[w] = b;
}

// ---------------- TN GEMM: C[M][N] = A[M][K] * B[N][K]^T (bf16 in, fp32 out) --------
// 64x128 tile, BK=64, 4 waves (2x2), 32x64 per wave, fragment-ordered LDS.
__global__ __launch_bounds__(256) void gemm_tn(const u16* __restrict__ A,
                                               const u16* __restrict__ B,
                                               float* __restrict__ C,
                                               int M, int N, int K) {
  __shared__ u16 As[64 * 64];    // 8 KB
  __shared__ u16 Bs[128 * 64];   // 16 KB
  const int tid = threadIdx.x;
  const int w = tid >> 6, l = tid & 63;
  const int bm = blockIdx.x, bn = blockIdx.y;
  const int wr = w >> 1, wc = w & 1;

  f32x4 acc[2][4] = {};

  int rowA[2], colA[2], ldsA[2];
#pragma unroll
  for (int g = 0; g < 2; ++g) {
    int c = g * 256 + w * 64 + l;
    rowA[g] = ((c >> 7) << 4) + (c & 15);
    colA[g] = ((c >> 4) & 7) * 8;
    ldsA[g] = (g * 256 + w * 64) * 8;
  }
  int rowB[4], colB[4], ldsB[4];
#pragma unroll
  for (int g = 0; g < 4; ++g) {
    int c = g * 256 + w * 64 + l;
    rowB[g] = ((c >> 7) << 4) + (c & 15);
    colB[g] = ((c >> 4) & 7) * 8;
    ldsB[g] = (g * 256 + w * 64) * 8;
  }
  const u16* Arow = A + (size_t)(bm * 64) * K;
  const u16* Brow = B + (size_t)(bn * 128) * K;

  for (int k0 = 0; k0 < K; k0 += 64) {
    __syncthreads();
#pragma unroll
    for (int g = 0; g < 2; ++g)
      gload_lds16(Arow + (size_t)rowA[g] * K + k0 + colA[g], &As[ldsA[g]]);
#pragma unroll
    for (int g = 0; g < 4; ++g)
      gload_lds16(Brow + (size_t)rowB[g] * K + k0 + colB[g], &Bs[ldsB[g]]);
    asm volatile("s_waitcnt vmcnt(0)" ::: "memory");
    __syncthreads();
#pragma unroll
    for (int ks = 0; ks < 2; ++ks) {
      bf16x8 af[2], bfr[4];
#pragma unroll
      for (int mi = 0; mi < 2; ++mi)
        af[mi] = *(const bf16x8*)&As[(wr * 2 + mi) * 1024 + ks * 512 + l * 8];
#pragma unroll
      for (int ni = 0; ni < 4; ++ni)
        bfr[ni] = *(const bf16x8*)&Bs[(wc * 4 + ni) * 1024 + ks * 512 + l * 8];
#pragma unroll
      for (int mi = 0; mi < 2; ++mi)
#pragma unroll
        for (int ni = 0; ni < 4; ++ni)
          acc[mi][ni] = __builtin_amdgcn_mfma_f32_16x16x32_bf16(af[mi], bfr[ni],
                                                                acc[mi][ni], 0, 0, 0);
    }
  }
  const int cr = (l >> 4) * 4, cc = l & 15;
#pragma unroll
  for (int mi = 0; mi < 2; ++mi) {
    int row0 = bm * 64 + wr * 32 + mi * 16 + cr;
#pragma unroll
    for (int ni = 0; ni < 4; ++ni) {
      int col = bn * 128 + wc * 64 + ni * 16 + cc;
#pragma unroll
      for (int i = 0; i < 4; ++i)
        C[(size_t)(row0 + i) * N + col] = acc[mi][ni][i];
    }
  }
}

// ---------------- RoPE + RMSNorm epilogue ----------------
__global__ __launch_bounds__(256) void rope_rms(const float* __restrict__ qkv,
                                                const float* __restrict__ qw,
                                                const float* __restrict__ kw,
                                                u16* __restrict__ Qo,
                                                u16* __restrict__ Ko) {
  int s = blockIdx.x * 4 + (threadIdx.x >> 6);
  int hh = blockIdx.y;
  int d = threadIdx.x & 63;
  bool isq = hh < 32;
  int col = isq ? hh * 64 + d : 2048 + (hh - 32) * 64 + d;
  float x = qkv[(size_t)s * QKVN + col];
  int i = d & 31;
  float inv_freq = exp2f(-(float)i * (13.287712379549449f / 32.0f));
  float ang = (float)s * inv_freq;
  float sn, cs;
  __sincosf(ang, &sn, &cs);
  float partner = __shfl_xor(x, 32, 64);
  float y = (d < 32) ? (x * cs - partner * sn) : (x * cs + partner * sn);
  float ss = y * y;
#pragma unroll
  for (int off = 32; off; off >>= 1) ss += __shfl_xor(ss, off, 64);
  float r = rsqrtf(ss * (1.0f / 64.0f) + 1e-6f);
  float o = y * r * (isq ? qw[d] : kw[d]);
  if (isq) Qo[((size_t)hh * SLEN + s) * 64 + d] = f2bf(o * QSCALE);
  else     Ko[((size_t)(hh - 32) * SLEN + s) * 64 + d] = f2bf(o);
}

// V slice of QKV -> V^T bf16 [8][64][S]
__global__ __launch_bounds__(256) void v_trans(const float* __restrict__ qkv,
                                               u16* __restrict__ Vt) {
  __shared__ float tile[32][65];
  int kv = blockIdx.y;
  int s0 = blockIdx.x * 32;
  int tid = threadIdx.x;
  int d = tid & 63, r4 = tid >> 6;
#pragma unroll
  for (int i = 0; i < 32; i += 4)
    tile[i + r4][d] = qkv[(size_t)(s0 + i + r4) * QKVN + 2560 + kv * 64 + d];
  __syncthreads();
  int dr = tid >> 2, sc = (tid & 3) * 8;
  u16x8 o;
#pragma unroll
  for (int j = 0; j < 8; ++j) o[j] = f2bf(tile[sc + j][dr]);
  *(u16x8*)(Vt + ((size_t)(kv * 64 + dr)) * SLEN + s0 + sc) = o;
}

// ---------------- flash attention, split-K x2 (swapped 32x32, no LDS) ----------
// grid (8, 128): block (x,y) -> waves = heads x*4+w, all at (qt = 63-(y>>1),
// split s = y&1). Split0: kb in [0, h1), split1: [h1, qt+1), h1 = ceil((qt+1)/2).
// K, V, mask all prefetched one iter ahead; cross-half ops via permlane32_swap.
__global__ __launch_bounds__(256) void attn_split(const u16* __restrict__ Q,
                                                  const u16* __restrict__ Kh,
                                                  const u16* __restrict__ Vt,
                                                  const uint32_t* __restrict__ mbits,
                                                  float* __restrict__ pacc0,
                                                  float2* __restrict__ pml0,
                                                  float* __restrict__ pacc1,
                                                  float2* __restrict__ pml1) {
  const int w = threadIdx.x >> 6, l = threadIdx.x & 63;
  const int h = blockIdx.x * 4 + w;
  const int qt = 63 - (blockIdx.y >> 1);
  const int s_split = blockIdx.y & 1;
  const int q0 = qt * 32;
  const int hkv = h >> 2;
  const bool web = (h >= 16);
  const int l31 = l & 31, hi = l >> 5;
  const int qrel = l31 - 4 * hi;  // diag-block causal: keep iff ki <= qrel

  const int h1 = (qt + 2) >> 1;                 // ceil((qt+1)/2)
  const int kb0 = s_split ? h1 : 0;
  const int kbe = s_split ? (qt + 1) : h1;      // exclusive

  // Q B-frags (col=lane&31=q, k=hi*8+j), D=64 -> 4 frags
  const u16* Qp = Q + ((size_t)h * SLEN + q0 + l31) * 64 + hi * 8;
  bf16x8 qf0 = *(const bf16x8*)(Qp);
  bf16x8 qf1 = *(const bf16x8*)(Qp + 16);
  bf16x8 qf2 = *(const bf16x8*)(Qp + 32);
  bf16x8 qf3 = *(const bf16x8*)(Qp + 48);

  const u16* Kp = Kh + ((size_t)hkv * SLEN + l31) * 64 + hi * 8;
  const u16* Vp = Vt + ((size_t)hkv * 64 + l31) * SLEN + hi * 8;
  const uint32_t* mrow = mbits + (size_t)(q0 + l31) * 64;

  f32x16 acc0 = {}, acc1 = {};   // O^T[d][q]
  float m = -1e30f, ll = 0.f;

  if (kb0 < kbe) {
    // prefetch first K block, V block, mask word
    const u16* kp = Kp + (size_t)kb0 * 64 * 32;
    bf16x8 kc0 = *(const bf16x8*)(kp);
    bf16x8 kc1 = *(const bf16x8*)(kp + 16);
    bf16x8 kc2 = *(const bf16x8*)(kp + 32);
    bf16x8 kc3 = *(const bf16x8*)(kp + 48);
    const u16* vp0 = Vp + kb0 * 32;
    bf16x8 vc00 = *(const bf16x8*)(vp0);
    bf16x8 vc01 = *(const bf16x8*)(vp0 + 16);
    bf16x8 vc10 = *(const bf16x8*)(vp0 + 32 * SLEN);
    bf16x8 vc11 = *(const bf16x8*)(vp0 + 32 * SLEN + 16);
    uint32_t wcur = web ? mrow[kb0] : 0u;

    for (int kb = kb0; kb < kbe; ++kb) {
      // ---- prefetch next K, V, mask (consumed next iter) ----
      bf16x8 kn0, kn1, kn2, kn3, vn00, vn01, vn10, vn11;
      uint32_t wnext = 0u;
      if (kb + 1 < kbe) {
        const u16* knp = Kp + (size_t)(kb + 1) * 64 * 32;
        kn0 = *(const bf16x8*)(knp);
        kn1 = *(const bf16x8*)(knp + 16);
        kn2 = *(const bf16x8*)(knp + 32);
        kn3 = *(const bf16x8*)(knp + 48);
        const u16* vnp = Vp + (kb + 1) * 32;
        vn00 = *(const bf16x8*)(vnp);
        vn01 = *(const bf16x8*)(vnp + 16);
        vn10 = *(const bf16x8*)(vnp + 32 * SLEN);
        vn11 = *(const bf16x8*)(vnp + 32 * SLEN + 16);
        if (web) wnext = mrow[kb + 1];
      }
      // ---- S^T = K * Q ----
      f32x16 s = {};
      s = __builtin_amdgcn_mfma_f32_32x32x16_bf16(kc0, qf0, s, 0, 0, 0);
      s = __builtin_amdgcn_mfma_f32_32x32x16_bf16(kc1, qf1, s, 0, 0, 0);
      s = __builtin_amdgcn_mfma_f32_32x32x16_bf16(kc2, qf2, s, 0, 0, 0);
      s = __builtin_amdgcn_mfma_f32_32x32x16_bf16(kc3, qf3, s, 0, 0, 0);
      // ---- mask (exp2 domain; masked -> -1e9) ----
      if (web) {
        uint32_t word = wcur >> (hi * 4);
        if (kb == qt) {
#pragma unroll
          for (int r = 0; r < 16; ++r) {
            const int ki = (r & 3) + 8 * (r >> 2);
            bool keep = ((word >> ki) & 1u) && (ki <= qrel);
            s[r] = keep ? s[r] : -1e9f;
          }
        } else {
#pragma unroll
          for (int r = 0; r < 16; ++r) {
            const int ki = (r & 3) + 8 * (r >> 2);
            s[r] = ((word >> ki) & 1u) ? s[r] : -1e9f;
          }
        }
      } else if (kb == qt) {
#pragma unroll
        for (int r = 0; r < 16; ++r) {
          const int ki = (r & 3) + 8 * (r >> 2);
          s[r] = (ki <= qrel) ? s[r] : -1e9f;
        }
      }
      // ---- online softmax (lane-local row, permlane cross-half) ----
      float pm = s[0];
#pragma unroll
      for (int r = 1; r < 16; ++r) pm = fmaxf(pm, s[r]);
      pm = xhalf_max(pm);
      if (__any(pm > m + 8.0f)) {           // defer-max, log2 units
        float nm = fmaxf(m, pm);
        float al = exp2f(m - nm);
#pragma unroll
        for (int r = 0; r < 16; ++r) { acc0[r] *= al; acc1[r] *= al; }
        ll *= al;
        m = nm;
      }
      f32x16 p;
#pragma unroll
      for (int r = 0; r < 16; ++r) p[r] = exp2f(s[r] - m);
      float rs = 0.f;
#pragma unroll
      for (int r = 0; r < 16; ++r) rs += p[r];
      ll += xhalf_sum(rs);
      // ---- P^T -> bf16 B-frags via cvt_pk + permlane32_swap(lowpack, highpack) ----
      // swap(a,c): r[0] = a' = {lo: a-self, hi: partner c} = w_low
      //            r[1] = c' = {lo: partner a, hi: c-self} = w_high   (T12 recipe)
      uint32_t a0 = cvtpk_bf16(p[0], p[1]),   b0 = cvtpk_bf16(p[2], p[3]);
      uint32_t c0 = cvtpk_bf16(p[4], p[5]),   d0 = cvtpk_bf16(p[6], p[7]);
      uint32_t a1 = cvtpk_bf16(p[8], p[9]),   b1 = cvtpk_bf16(p[10], p[11]);
      uint32_t c1 = cvtpk_bf16(p[12], p[13]), d1 = cvtpk_bf16(p[14], p[15]);
      auto r0 = __builtin_amdgcn_permlane32_swap(a0, c0, false, false);
      auto r1 = __builtin_amdgcn_permlane32_swap(b0, d0, false, false);
      auto r2 = __builtin_amdgcn_permlane32_swap(a1, c1, false, false);
      auto r3 = __builtin_amdgcn_permlane32_swap(b1, d1, false, false);
      union { uint32_t w[4]; bf16x8 v; } pf0u, pf1u;
      pf0u.w[0] = r0[0]; pf0u.w[1] = r1[0]; pf0u.w[2] = r0[1]; pf0u.w[3] = r1[1];
      pf1u.w[0] = r2[0]; pf1u.w[1] = r3[0]; pf1u.w[2] = r2[1]; pf1u.w[3] = r3[1];
      // ---- O^T += V^T * P^T ----
      acc0 = __builtin_amdgcn_mfma_f32_32x32x16_bf16(vc00, pf0u.v, acc0, 0, 0, 0);
      acc0 = __builtin_amdgcn_mfma_f32_32x32x16_bf16(vc01, pf1u.v, acc0, 0, 0, 0);
      acc1 = __builtin_amdgcn_mfma_f32_32x32x16_bf16(vc10, pf0u.v, acc1, 0, 0, 0);
      acc1 = __builtin_amdgcn_mfma_f32_32x32x16_bf16(vc11, pf1u.v, acc1, 0, 0, 0);
      // rotate prefetch
      kc0 = kn0; kc1 = kn1; kc2 = kn2; kc3 = kn3;
      vc00 = vn00; vc01 = vn01; vc10 = vn10; vc11 = vn11;
      wcur = wnext;
    }
  }
  // ---- store partials (always, even for empty split) ----
  float* pacc = s_split ? pacc1 : pacc0;
  float2* pml = s_split ? pml1 : pml0;
  const size_t ridx = ((size_t)h * 64 + qt) * 32 + l31;
  float* base = pacc + ridx * 64;
#pragma unroll
  for (int t = 0; t < 4; ++t) {
    float4 v0 = {acc0[4 * t], acc0[4 * t + 1], acc0[4 * t + 2], acc0[4 * t + 3]};
    float4 v1 = {acc1[4 * t], acc1[4 * t + 1], acc1[4 * t + 2], acc1[4 * t + 3]};
    *(float4*)(base + 8 * t + 4 * hi) = v0;        // d = 8t+4hi..+3
    *(float4*)(base + 32 + 8 * t + 4 * hi) = v1;   // d = 32+8t+4hi..+3
  }
  if (hi == 0) pml[ridx] = make_float2(m, ll);
}

// ---------------- combine split-K partials -> Ao bf16 [S][H*D] ----------------
__global__ __launch_bounds__(256) void attn_combine(const float* __restrict__ pacc0,
                                                    const float2* __restrict__ pml0,
                                                    const float* __restrict__ pacc1,
                                                    const float2* __restrict__ pml1,
                                                    u16* __restrict__ Aout) {
  int gid = blockIdx.x * 256 + threadIdx.x;  // 65536 = 32h * 2048 rows
  int h = gid >> 11, srow = gid & 2047;
  float2 ml0 = pml0[gid], ml1 = pml1[gid];
  float M = fmaxf(ml0.x, ml1.x);
  float w0 = exp2f(ml0.x - M), w1 = exp2f(ml1.x - M);
  float inv = 1.0f / (ml0.y * w0 + ml1.y * w1);
  w0 *= inv; w1 *= inv;
  const float4* a0 = (const float4*)(pacc0 + (size_t)gid * 64);
  const float4* a1 = (const float4*)(pacc1 + (size_t)gid * 64);
  u16* orow = Aout + (size_t)srow * HIDDEN + h * 64;
#pragma unroll
  for (int t = 0; t < 16; ++t) {
    float4 x0 = a0[t], x1 = a1[t];
    float o0 = w0 * x0.x + w1 * x1.x;
    float o1 = w0 * x0.y + w1 * x1.y;
    float o2 = w0 * x0.z + w1 * x1.z;
    float o3 = w0 * x0.w + w1 * x1.w;
    uint2 pk;
    pk.x = cvtpk_bf16(o0, o1);
    pk.y = cvtpk_bf16(o2, o3);
    *(uint2*)(orow + t * 4) = pk;
  }
}

// ---------------- launch ----------------

extern "C" void kernel_launch(void* const* d_in, const int* in_sizes, int n_in,
                              void* d_out, int out_size, void* d_ws, size_t ws_size,
                              hipStream_t stream) {
  const float* hidden  = (const float*)d_in[0];
  const float* webmask = (const float*)d_in[3];
  const float* Wq = (const float*)d_in[4];
  const float* Wk = (const float*)d_in[5];
  const float* Wv = (const float*)d_in[6];
  const float* Wo = (const float*)d_in[7];
  const float* qlnw = (const float*)d_in[8];
  const float* klnw = (const float*)d_in[9];
  float* out = (float*)d_out;

  char* ws = (char*)d_ws;
  u16*      hbf  = (u16*)(ws);                         // 8 MB  hidden bf16 (dead after QKV gemm)
  u16*      Wcat = (u16*)(ws + (8u << 20));            // 12 MB QKV weights^T (dead after QKV gemm)
  u16*      Wot  = (u16*)(ws + (20u << 20));           // 8 MB  Wo^T (live until final gemm)
  float*    qkv  = (float*)(ws + (28u << 20));         // 24 MB QKV fp32 (dead after rope/v_trans)
  u16*      Qh   = (u16*)(ws + (52u << 20));           // 8 MB  Q' (pre-scaled)
  u16*      Kh   = (u16*)(ws + (60u << 20));           // 2 MB  K'
  u16*      Vt   = (u16*)(ws + (62u << 20));           // 2 MB  V^T
  u16*      Ao   = (u16*)(ws + (64u << 20));           // 8 MB  attn out bf16
  uint32_t* mb   = (uint32_t*)(ws + (72u << 20));      // 0.5 MB web mask bits
  // split-K partials overlay dead regions:
  float*    pa0  = (float*)(ws);                       // 16.78 MB over hbf+Wcat
  float2*   pm0  = (float2*)(ws + (17u << 20));        // 0.53 MB (Wcat region)
  float*    pa1  = (float*)(ws + (28u << 20));         // 16.78 MB over qkv
  float2*   pm1  = (float2*)(ws + (45u << 20));        // 0.53 MB (qkv region)

  cvt_f32_bf16<<<4096, 256, 0, stream>>>(hidden, hbf);
  transpose_w<<<dim3(64, 64), 256, 0, stream>>>(Wq, 2048, Wcat, 2048);
  transpose_w<<<dim3(64, 16), 256, 0, stream>>>(Wk, 512, Wcat + (size_t)2048 * 2048, 2048);
  transpose_w<<<dim3(64, 16), 256, 0, stream>>>(Wv, 512, Wcat + (size_t)2560 * 2048, 2048);
  transpose_w<<<dim3(64, 64), 256, 0, stream>>>(Wo, 2048, Wot, 2048);
  pack_mask<<<512, 256, 0, stream>>>(webmask, mb);

  gemm_tn<<<dim3(32, 24), 256, 0, stream>>>(hbf, Wcat, qkv, SLEN, QKVN, HIDDEN);
  rope_rms<<<dim3(512, 40), 256, 0, stream>>>(qkv, qlnw, klnw, Qh, Kh);
  v_trans<<<dim3(64, 8), 256, 0, stream>>>(qkv, Vt);
  attn_split<<<dim3(8, 128), 256, 0, stream>>>(Qh, Kh, Vt, mb, pa0, pm0, pa1, pm1);
  attn_combine<<<256, 256, 0, stream>>>(pa0, pm0, pa1, pm1, Ao);
  gemm_tn<<<dim3(32, 16), 256, 0, stream>>>(Ao, Wot, out, SLEN, HIDDEN, HIDDEN);
}

// Round 9
// 249.843 us; speedup vs baseline: 1.0877x; 1.0287x over previous
//
#include <hip/hip_runtime.h>
#include <stdint.h>

// WebAttention fused block for MI355X (gfx950).
// R9: attention -> in-block split-K x4: block = (head, q-tile), 4 waves take
//     interleaved key-blocks (kb = w, w+4, ...), combine via LDS (raw acc +
//     per-wave m,l -> weighted sum), write Ao directly. Uniform block durations,
//     no HBM partials, no combine kernel. Loop body identical to R8 (verified).

typedef unsigned short u16;
typedef unsigned short u16x4 __attribute__((ext_vector_type(4)));
typedef unsigned short u16x8 __attribute__((ext_vector_type(8)));
typedef __bf16 bf16x8 __attribute__((ext_vector_type(8)));
typedef float f32x4 __attribute__((ext_vector_type(4)));
typedef float f32x16 __attribute__((ext_vector_type(16)));

#define SLEN 2048
#define HIDDEN 2048
#define QKVN 3072   // 2048 Q + 512 K + 512 V
// Q pre-scale: 1/sqrt(64) * log2(e)  -> scores land in exp2 domain
#define QSCALE 0.18033688011112042f

__device__ __forceinline__ u16 f2bf(float x) {  // RNE, matches numpy/JAX
  uint32_t u = __float_as_uint(x);
  return (u16)((u + 0x7FFFu + ((u >> 16) & 1u)) >> 16);
}

__device__ __forceinline__ uint32_t cvtpk_bf16(float lo, float hi) {
  uint32_t r;
  asm("v_cvt_pk_bf16_f32 %0, %1, %2" : "=v"(r) : "v"(lo), "v"(hi));
  return r;
}

// Cross-half (lane ^ 32) reductions: {r[0],r[1]} = {self, partner} as a set.
__device__ __forceinline__ float xhalf_max(float x) {
  auto r = __builtin_amdgcn_permlane32_swap(__float_as_uint(x), __float_as_uint(x),
                                            false, false);
  return fmaxf(__uint_as_float(r[0]), __uint_as_float(r[1]));
}

__device__ __forceinline__ float xhalf_sum(float x) {
  auto r = __builtin_amdgcn_permlane32_swap(__float_as_uint(x), __float_as_uint(x),
                                            false, false);
  return __uint_as_float(r[0]) + __uint_as_float(r[1]);
}

__device__ __forceinline__ void gload_lds16(const void* g, void* l) {
  __builtin_amdgcn_global_load_lds(
      (const __attribute__((address_space(1))) void*)g,
      (__attribute__((address_space(3))) void*)l, 16, 0, 0);
}

// ---------------- prep kernels ----------------

__global__ __launch_bounds__(256) void cvt_f32_bf16(const float* __restrict__ in,
                                                    u16* __restrict__ out) {
  int idx = (blockIdx.x * 256 + threadIdx.x) * 4;
  float4 v = *(const float4*)(in + idx);
  u16x4 o;
  o[0] = f2bf(v.x); o[1] = f2bf(v.y); o[2] = f2bf(v.z); o[3] = f2bf(v.w);
  *(u16x4*)(out + idx) = o;
}

// in: f32 [K][ldin] row-major; out: bf16 [N][ldout] = transpose. grid (K/32, N/32).
__global__ __launch_bounds__(256) void transpose_w(const float* __restrict__ in, int ldin,
                                                   u16* __restrict__ out, int ldout) {
  __shared__ float tile[32][33];
  int k0 = blockIdx.x * 32, n0 = blockIdx.y * 32;
  int x = threadIdx.x & 31, y = threadIdx.x >> 5;  // y in 0..7
#pragma unroll
  for (int i = 0; i < 32; i += 8)
    tile[y + i][x] = in[(size_t)(k0 + y + i) * ldin + n0 + x];
  __syncthreads();
#pragma unroll
  for (int i = 0; i < 32; i += 8)
    out[(size_t)(n0 + y + i) * ldout + k0 + x] = f2bf(tile[x][y + i]);
}

// web mask [S][S] f32 (0 / -1e9) -> bitmask [S][64] u32 (bit=1 -> keep)
__global__ __launch_bounds__(256) void pack_mask(const float* __restrict__ m,
                                                 uint32_t* __restrict__ bits) {
  int w = blockIdx.x * 256 + threadIdx.x;  // 2048*64 words
  const float* p = m + (size_t)w * 32;
  uint32_t b = 0;
#pragma unroll
  for (int j = 0; j < 32; ++j) b |= (p[j] > -0.5f ? 1u : 0u) << j;
  bits[w] = b;
}

// ---------------- TN GEMM: C[M][N] = A[M][K] * B[N][K]^T (bf16 in, fp32 out) --------
// 64x128 tile, BK=64, 4 waves (2x2), 32x64 per wave, fragment-ordered LDS.
__global__ __launch_bounds__(256) void gemm_tn(const u16* __restrict__ A,
                                               const u16* __restrict__ B,
                                               float* __restrict__ C,
                                               int M, int N, int K) {
  __shared__ u16 As[64 * 64];    // 8 KB
  __shared__ u16 Bs[128 * 64];   // 16 KB
  const int tid = threadIdx.x;
  const int w = tid >> 6, l = tid & 63;
  const int bm = blockIdx.x, bn = blockIdx.y;
  const int wr = w >> 1, wc = w & 1;

  f32x4 acc[2][4] = {};

  int rowA[2], colA[2], ldsA[2];
#pragma unroll
  for (int g = 0; g < 2; ++g) {
    int c = g * 256 + w * 64 + l;
    rowA[g] = ((c >> 7) << 4) + (c & 15);
    colA[g] = ((c >> 4) & 7) * 8;
    ldsA[g] = (g * 256 + w * 64) * 8;
  }
  int rowB[4], colB[4], ldsB[4];
#pragma unroll
  for (int g = 0; g < 4; ++g) {
    int c = g * 256 + w * 64 + l;
    rowB[g] = ((c >> 7) << 4) + (c & 15);
    colB[g] = ((c >> 4) & 7) * 8;
    ldsB[g] = (g * 256 + w * 64) * 8;
  }
  const u16* Arow = A + (size_t)(bm * 64) * K;
  const u16* Brow = B + (size_t)(bn * 128) * K;

  for (int k0 = 0; k0 < K; k0 += 64) {
    __syncthreads();
#pragma unroll
    for (int g = 0; g < 2; ++g)
      gload_lds16(Arow + (size_t)rowA[g] * K + k0 + colA[g], &As[ldsA[g]]);
#pragma unroll
    for (int g = 0; g < 4; ++g)
      gload_lds16(Brow + (size_t)rowB[g] * K + k0 + colB[g], &Bs[ldsB[g]]);
    asm volatile("s_waitcnt vmcnt(0)" ::: "memory");
    __syncthreads();
#pragma unroll
    for (int ks = 0; ks < 2; ++ks) {
      bf16x8 af[2], bfr[4];
#pragma unroll
      for (int mi = 0; mi < 2; ++mi)
        af[mi] = *(const bf16x8*)&As[(wr * 2 + mi) * 1024 + ks * 512 + l * 8];
#pragma unroll
      for (int ni = 0; ni < 4; ++ni)
        bfr[ni] = *(const bf16x8*)&Bs[(wc * 4 + ni) * 1024 + ks * 512 + l * 8];
#pragma unroll
      for (int mi = 0; mi < 2; ++mi)
#pragma unroll
        for (int ni = 0; ni < 4; ++ni)
          acc[mi][ni] = __builtin_amdgcn_mfma_f32_16x16x32_bf16(af[mi], bfr[ni],
                                                                acc[mi][ni], 0, 0, 0);
    }
  }
  const int cr = (l >> 4) * 4, cc = l & 15;
#pragma unroll
  for (int mi = 0; mi < 2; ++mi) {
    int row0 = bm * 64 + wr * 32 + mi * 16 + cr;
#pragma unroll
    for (int ni = 0; ni < 4; ++ni) {
      int col = bn * 128 + wc * 64 + ni * 16 + cc;
#pragma unroll
      for (int i = 0; i < 4; ++i)
        C[(size_t)(row0 + i) * N + col] = acc[mi][ni][i];
    }
  }
}

// ---------------- RoPE + RMSNorm epilogue ----------------
__global__ __launch_bounds__(256) void rope_rms(const float* __restrict__ qkv,
                                                const float* __restrict__ qw,
                                                const float* __restrict__ kw,
                                                u16* __restrict__ Qo,
                                                u16* __restrict__ Ko) {
  int s = blockIdx.x * 4 + (threadIdx.x >> 6);
  int hh = blockIdx.y;
  int d = threadIdx.x & 63;
  bool isq = hh < 32;
  int col = isq ? hh * 64 + d : 2048 + (hh - 32) * 64 + d;
  float x = qkv[(size_t)s * QKVN + col];
  int i = d & 31;
  float inv_freq = exp2f(-(float)i * (13.287712379549449f / 32.0f));
  float ang = (float)s * inv_freq;
  float sn, cs;
  __sincosf(ang, &sn, &cs);
  float partner = __shfl_xor(x, 32, 64);
  float y = (d < 32) ? (x * cs - partner * sn) : (x * cs + partner * sn);
  float ss = y * y;
#pragma unroll
  for (int off = 32; off; off >>= 1) ss += __shfl_xor(ss, off, 64);
  float r = rsqrtf(ss * (1.0f / 64.0f) + 1e-6f);
  float o = y * r * (isq ? qw[d] : kw[d]);
  if (isq) Qo[((size_t)hh * SLEN + s) * 64 + d] = f2bf(o * QSCALE);
  else     Ko[((size_t)(hh - 32) * SLEN + s) * 64 + d] = f2bf(o);
}

// V slice of QKV -> V^T bf16 [8][64][S]
__global__ __launch_bounds__(256) void v_trans(const float* __restrict__ qkv,
                                               u16* __restrict__ Vt) {
  __shared__ float tile[32][65];
  int kv = blockIdx.y;
  int s0 = blockIdx.x * 32;
  int tid = threadIdx.x;
  int d = tid & 63, r4 = tid >> 6;
#pragma unroll
  for (int i = 0; i < 32; i += 4)
    tile[i + r4][d] = qkv[(size_t)(s0 + i + r4) * QKVN + 2560 + kv * 64 + d];
  __syncthreads();
  int dr = tid >> 2, sc = (tid & 3) * 8;
  u16x8 o;
#pragma unroll
  for (int j = 0; j < 8; ++j) o[j] = f2bf(tile[sc + j][dr]);
  *(u16x8*)(Vt + ((size_t)(kv * 64 + dr)) * SLEN + s0 + sc) = o;
}

// ---------------- flash attention, in-block split-K x4 ----------------
// grid (32 heads, 64): block (h, qt=63-by). Wave w takes kb = w, w+4, ...
// (interleaved; per-wave counts differ by <=1). Raw acc + (m,l) -> LDS;
// single barrier; weighted combine; Ao written directly (bf16).
// LDS acc layout swizzled: off(q,d) = q*64 + (d ^ ((q&15)<<2)).
__global__ __launch_bounds__(256) void attn_fused(const u16* __restrict__ Q,
                                                  const u16* __restrict__ Kh,
                                                  const u16* __restrict__ Vt,
                                                  const uint32_t* __restrict__ mbits,
                                                  u16* __restrict__ Aout) {
  __shared__ float accS[4 * 32 * 64];  // 32 KB
  __shared__ float2 mlS[4 * 32];       // 1 KB
  const int w = threadIdx.x >> 6, l = threadIdx.x & 63;
  const int h = blockIdx.x;
  const int qt = 63 - blockIdx.y;      // longest blocks dispatched first
  const int q0 = qt * 32;
  const int hkv = h >> 2;
  const bool web = (h >= 16);
  const int l31 = l & 31, hi = l >> 5;
  const int qrel = l31 - 4 * hi;  // diag-block causal: keep iff ki <= qrel
  const int nkb = qt + 1;

  // Q B-frags (col=lane&31=q, k=hi*8+j), D=64 -> 4 frags
  const u16* Qp = Q + ((size_t)h * SLEN + q0 + l31) * 64 + hi * 8;
  bf16x8 qf0 = *(const bf16x8*)(Qp);
  bf16x8 qf1 = *(const bf16x8*)(Qp + 16);
  bf16x8 qf2 = *(const bf16x8*)(Qp + 32);
  bf16x8 qf3 = *(const bf16x8*)(Qp + 48);

  const u16* Kp = Kh + ((size_t)hkv * SLEN + l31) * 64 + hi * 8;
  const u16* Vp = Vt + ((size_t)hkv * 64 + l31) * SLEN + hi * 8;
  const uint32_t* mrow = mbits + (size_t)(q0 + l31) * 64;

  f32x16 acc0 = {}, acc1 = {};   // O^T[d][q]
  float m = -1e30f, ll = 0.f;

  if (w < nkb) {
    // prefetch first K block, V block, mask word
    const u16* kp = Kp + (size_t)w * 64 * 32;
    bf16x8 kc0 = *(const bf16x8*)(kp);
    bf16x8 kc1 = *(const bf16x8*)(kp + 16);
    bf16x8 kc2 = *(const bf16x8*)(kp + 32);
    bf16x8 kc3 = *(const bf16x8*)(kp + 48);
    const u16* vp0 = Vp + w * 32;
    bf16x8 vc00 = *(const bf16x8*)(vp0);
    bf16x8 vc01 = *(const bf16x8*)(vp0 + 16);
    bf16x8 vc10 = *(const bf16x8*)(vp0 + 32 * SLEN);
    bf16x8 vc11 = *(const bf16x8*)(vp0 + 32 * SLEN + 16);
    uint32_t wcur = web ? mrow[w] : 0u;

    for (int kb = w; kb < nkb; kb += 4) {
      // ---- prefetch next K, V, mask (consumed next iter) ----
      bf16x8 kn0, kn1, kn2, kn3, vn00, vn01, vn10, vn11;
      uint32_t wnext = 0u;
      if (kb + 4 < nkb) {
        const u16* knp = Kp + (size_t)(kb + 4) * 64 * 32;
        kn0 = *(const bf16x8*)(knp);
        kn1 = *(const bf16x8*)(knp + 16);
        kn2 = *(const bf16x8*)(knp + 32);
        kn3 = *(const bf16x8*)(knp + 48);
        const u16* vnp = Vp + (kb + 4) * 32;
        vn00 = *(const bf16x8*)(vnp);
        vn01 = *(const bf16x8*)(vnp + 16);
        vn10 = *(const bf16x8*)(vnp + 32 * SLEN);
        vn11 = *(const bf16x8*)(vnp + 32 * SLEN + 16);
        if (web) wnext = mrow[kb + 4];
      }
      // ---- S^T = K * Q ----
      f32x16 s = {};
      s = __builtin_amdgcn_mfma_f32_32x32x16_bf16(kc0, qf0, s, 0, 0, 0);
      s = __builtin_amdgcn_mfma_f32_32x32x16_bf16(kc1, qf1, s, 0, 0, 0);
      s = __builtin_amdgcn_mfma_f32_32x32x16_bf16(kc2, qf2, s, 0, 0, 0);
      s = __builtin_amdgcn_mfma_f32_32x32x16_bf16(kc3, qf3, s, 0, 0, 0);
      // ---- mask (exp2 domain; masked -> -1e9) ----
      if (web) {
        uint32_t word = wcur >> (hi * 4);
        if (kb == qt) {
#pragma unroll
          for (int r = 0; r < 16; ++r) {
            const int ki = (r & 3) + 8 * (r >> 2);
            bool keep = ((word >> ki) & 1u) && (ki <= qrel);
            s[r] = keep ? s[r] : -1e9f;
          }
        } else {
#pragma unroll
          for (int r = 0; r < 16; ++r) {
            const int ki = (r & 3) + 8 * (r >> 2);
            s[r] = ((word >> ki) & 1u) ? s[r] : -1e9f;
          }
        }
      } else if (kb == qt) {
#pragma unroll
        for (int r = 0; r < 16; ++r) {
          const int ki = (r & 3) + 8 * (r >> 2);
          s[r] = (ki <= qrel) ? s[r] : -1e9f;
        }
      }
      // ---- online softmax (lane-local row, permlane cross-half) ----
      float pm = s[0];
#pragma unroll
      for (int r = 1; r < 16; ++r) pm = fmaxf(pm, s[r]);
      pm = xhalf_max(pm);
      if (__any(pm > m + 8.0f)) {           // defer-max, log2 units
        float nm = fmaxf(m, pm);
        float al = exp2f(m - nm);
#pragma unroll
        for (int r = 0; r < 16; ++r) { acc0[r] *= al; acc1[r] *= al; }
        ll *= al;
        m = nm;
      }
      f32x16 p;
#pragma unroll
      for (int r = 0; r < 16; ++r) p[r] = exp2f(s[r] - m);
      float rs = 0.f;
#pragma unroll
      for (int r = 0; r < 16; ++r) rs += p[r];
      ll += xhalf_sum(rs);
      // ---- P^T -> bf16 B-frags via cvt_pk + permlane32_swap(lowpack, highpack) ----
      uint32_t a0 = cvtpk_bf16(p[0], p[1]),   b0 = cvtpk_bf16(p[2], p[3]);
      uint32_t c0 = cvtpk_bf16(p[4], p[5]),   d0 = cvtpk_bf16(p[6], p[7]);
      uint32_t a1 = cvtpk_bf16(p[8], p[9]),   b1 = cvtpk_bf16(p[10], p[11]);
      uint32_t c1 = cvtpk_bf16(p[12], p[13]), d1 = cvtpk_bf16(p[14], p[15]);
      auto r0 = __builtin_amdgcn_permlane32_swap(a0, c0, false, false);
      auto r1 = __builtin_amdgcn_permlane32_swap(b0, d0, false, false);
      auto r2 = __builtin_amdgcn_permlane32_swap(a1, c1, false, false);
      auto r3 = __builtin_amdgcn_permlane32_swap(b1, d1, false, false);
      union { uint32_t w[4]; bf16x8 v; } pf0u, pf1u;
      pf0u.w[0] = r0[0]; pf0u.w[1] = r1[0]; pf0u.w[2] = r0[1]; pf0u.w[3] = r1[1];
      pf1u.w[0] = r2[0]; pf1u.w[1] = r3[0]; pf1u.w[2] = r2[1]; pf1u.w[3] = r3[1];
      // ---- O^T += V^T * P^T ----
      acc0 = __builtin_amdgcn_mfma_f32_32x32x16_bf16(vc00, pf0u.v, acc0, 0, 0, 0);
      acc0 = __builtin_amdgcn_mfma_f32_32x32x16_bf16(vc01, pf1u.v, acc0, 0, 0, 0);
      acc1 = __builtin_amdgcn_mfma_f32_32x32x16_bf16(vc10, pf0u.v, acc1, 0, 0, 0);
      acc1 = __builtin_amdgcn_mfma_f32_32x32x16_bf16(vc11, pf1u.v, acc1, 0, 0, 0);
      // rotate prefetch
      kc0 = kn0; kc1 = kn1; kc2 = kn2; kc3 = kn3;
      vc00 = vn00; vc01 = vn01; vc10 = vn10; vc11 = vn11;
      wcur = wnext;
    }
  }
  // ---- stash per-wave state in LDS (raw acc + m,l) ----
  if (hi == 0) mlS[w * 32 + l31] = make_float2(m, ll);
  float* wbase = accS + w * 2048 + (l31 << 6);
  const int sw = (l31 & 15) << 2;  // swizzle: d ^= sw
#pragma unroll
  for (int t = 0; t < 4; ++t) {
    int dA = (8 * t + 4 * hi) ^ sw;
    int dB = (32 + 8 * t + 4 * hi) ^ sw;
    float4 v0 = {acc0[4 * t], acc0[4 * t + 1], acc0[4 * t + 2], acc0[4 * t + 3]};
    float4 v1 = {acc1[4 * t], acc1[4 * t + 1], acc1[4 * t + 2], acc1[4 * t + 3]};
    *(float4*)(wbase + dA) = v0;
    *(float4*)(wbase + dB) = v1;
  }
  __syncthreads();
  // ---- combine: thread -> (q = tid&31, d = (tid>>5)*8) ----
  const int q = threadIdx.x & 31;
  const int dd = (threadIdx.x >> 5) * 8;
  float2 ml0 = mlS[q], ml1 = mlS[32 + q], ml2 = mlS[64 + q], ml3 = mlS[96 + q];
  float M = fmaxf(fmaxf(ml0.x, ml1.x), fmaxf(ml2.x, ml3.x));
  float w0 = exp2f(ml0.x - M), w1 = exp2f(ml1.x - M);
  float w2 = exp2f(ml2.x - M), w3 = exp2f(ml3.x - M);
  float L = ml0.y * w0 + ml1.y * w1 + ml2.y * w2 + ml3.y * w3;
  const int offA = (q << 6) + (dd ^ ((q & 15) << 2));
  const int offB = offA ^ 4;
  float o[8];
  {
    float4 xa = *(float4*)(accS + offA);
    float4 xb = *(float4*)(accS + offB);
    o[0] = w0 * xa.x; o[1] = w0 * xa.y; o[2] = w0 * xa.z; o[3] = w0 * xa.w;
    o[4] = w0 * xb.x; o[5] = w0 * xb.y; o[6] = w0 * xb.z; o[7] = w0 * xb.w;
  }
  {
    float4 xa = *(float4*)(accS + 2048 + offA);
    float4 xb = *(float4*)(accS + 2048 + offB);
    o[0] += w1 * xa.x; o[1] += w1 * xa.y; o[2] += w1 * xa.z; o[3] += w1 * xa.w;
    o[4] += w1 * xb.x; o[5] += w1 * xb.y; o[6] += w1 * xb.z; o[7] += w1 * xb.w;
  }
  {
    float4 xa = *(float4*)(accS + 4096 + offA);
    float4 xb = *(float4*)(accS + 4096 + offB);
    o[0] += w2 * xa.x; o[1] += w2 * xa.y; o[2] += w2 * xa.z; o[3] += w2 * xa.w;
    o[4] += w2 * xb.x; o[5] += w2 * xb.y; o[6] += w2 * xb.z; o[7] += w2 * xb.w;
  }
  {
    float4 xa = *(float4*)(accS + 6144 + offA);
    float4 xb = *(float4*)(accS + 6144 + offB);
    o[0] += w3 * xa.x; o[1] += w3 * xa.y; o[2] += w3 * xa.z; o[3] += w3 * xa.w;
    o[4] += w3 * xb.x; o[5] += w3 * xb.y; o[6] += w3 * xb.z; o[7] += w3 * xb.w;
  }
  const float invL = 1.0f / L;
  uint4 pk;
  pk.x = cvtpk_bf16(o[0] * invL, o[1] * invL);
  pk.y = cvtpk_bf16(o[2] * invL, o[3] * invL);
  pk.z = cvtpk_bf16(o[4] * invL, o[5] * invL);
  pk.w = cvtpk_bf16(o[6] * invL, o[7] * invL);
  *(uint4*)(Aout + (size_t)(q0 + q) * HIDDEN + h * 64 + dd) = pk;
}

// ---------------- launch ----------------

extern "C" void kernel_launch(void* const* d_in, const int* in_sizes, int n_in,
                              void* d_out, int out_size, void* d_ws, size_t ws_size,
                              hipStream_t stream) {
  const float* hidden  = (const float*)d_in[0];
  const float* webmask = (const float*)d_in[3];
  const float* Wq = (const float*)d_in[4];
  const float* Wk = (const float*)d_in[5];
  const float* Wv = (const float*)d_in[6];
  const float* Wo = (const float*)d_in[7];
  const float* qlnw = (const float*)d_in[8];
  const float* klnw = (const float*)d_in[9];
  float* out = (float*)d_out;

  char* ws = (char*)d_ws;
  u16*      hbf  = (u16*)(ws);                         // 8 MB  hidden bf16
  u16*      Wcat = (u16*)(ws + (8u << 20));            // 12 MB QKV weights^T
  u16*      Wot  = (u16*)(ws + (20u << 20));           // 8 MB  Wo^T
  float*    qkv  = (float*)(ws + (28u << 20));         // 24 MB QKV fp32
  u16*      Qh   = (u16*)(ws + (52u << 20));           // 8 MB  Q' (pre-scaled)
  u16*      Kh   = (u16*)(ws + (60u << 20));           // 2 MB  K'
  u16*      Vt   = (u16*)(ws + (62u << 20));           // 2 MB  V^T
  u16*      Ao   = (u16*)(ws + (64u << 20));           // 8 MB  attn out bf16
  uint32_t* mb   = (uint32_t*)(ws + (72u << 20));      // 0.5 MB web mask bits

  cvt_f32_bf16<<<4096, 256, 0, stream>>>(hidden, hbf);
  transpose_w<<<dim3(64, 64), 256, 0, stream>>>(Wq, 2048, Wcat, 2048);
  transpose_w<<<dim3(64, 16), 256, 0, stream>>>(Wk, 512, Wcat + (size_t)2048 * 2048, 2048);
  transpose_w<<<dim3(64, 16), 256, 0, stream>>>(Wv, 512, Wcat + (size_t)2560 * 2048, 2048);
  transpose_w<<<dim3(64, 64), 256, 0, stream>>>(Wo, 2048, Wot, 2048);
  pack_mask<<<512, 256, 0, stream>>>(webmask, mb);

  gemm_tn<<<dim3(32, 24), 256, 0, stream>>>(hbf, Wcat, qkv, SLEN, QKVN, HIDDEN);
  rope_rms<<<dim3(512, 40), 256, 0, stream>>>(qkv, qlnw, klnw, Qh, Kh);
  v_trans<<<dim3(64, 8), 256, 0, stream>>>(qkv, Vt);
  attn_fused<<<dim3(32, 64), 256, 0, stream>>>(Qh, Kh, Vt, mb, Ao);
  gemm_tn<<<dim3(32, 16), 256, 0, stream>>>(Ao, Wot, out, SLEN, HIDDEN, HIDDEN);
}